// Round 6
// baseline (315.358 us; speedup 1.0000x reference)
//
#include <hip/hip_runtime.h>
#include <math.h>
#include <float.h>

// Problem dims (fixed by setup_inputs)
#define BB 32
#define TT 2048
#define OO 128
#define CC 80
#define EPSF 1e-7f
#define NT 256
#define CPAD 81           // LDS class-row stride: conflict-free
#define TPT 128           // tokens per cost tile
#define NTILE 16          // cost t-tiles (TT/TPT)
#define INVP 0xFFFFFFFFFFFFFFFFull

typedef float vf4 __attribute__((ext_vector_type(4)));
typedef unsigned long long u64;

// DPP lexicographic-min (val,idx) f64 — disjoint aggregation chain into lane 63.
template<int CTRL>
__device__ __forceinline__ void dpp_lexmin(double& bv, int& bj) {
    int lo = __double2loint(bv), hi = __double2hiint(bv);
    int tlo = __builtin_amdgcn_update_dpp(0, lo, CTRL, 0xF, 0xF, false);
    int thi = __builtin_amdgcn_update_dpp(0x7FF00000, hi, CTRL, 0xF, 0xF, false);
    int tj  = __builtin_amdgcn_update_dpp(0x7FFFFFFF, bj, CTRL, 0xF, 0xF, false);
    double tv = __hiloint2double(thi, tlo);
    if (tv < bv || (tv == bv && tj < bj)) { bv = tv; bj = tj; }
}

// f32 (val,idx) lexmin for the producer's row-min reduction.
template<int CTRL>
__device__ __forceinline__ void dpp_lexmin_f32(float& bv, int& bj) {
    int tlo = __builtin_amdgcn_update_dpp(0x7F800000, __float_as_int(bv), CTRL, 0xF, 0xF, false);
    int tj  = __builtin_amdgcn_update_dpp(0x7FFFFFFF, bj, CTRL, 0xF, 0xF, false);
    float tv = __int_as_float(tlo);
    if (tv < bv || (tv == bv && tj < bj)) { bv = tv; bj = tj; }
}

// u64-pack top-2 (packs = (f32bits<<32)|col, cost>0 so ordering is exact/lex).
template<int CTRL>
__device__ __forceinline__ void dpp_top2_u64(u64& p1, u64& p2) {
    int t1lo = __builtin_amdgcn_update_dpp((int)0xFFFFFFFF, (int)(unsigned)(p1 & 0xFFFFFFFFull), CTRL, 0xF, 0xF, false);
    int t1hi = __builtin_amdgcn_update_dpp((int)0xFFFFFFFF, (int)(unsigned)(p1 >> 32), CTRL, 0xF, 0xF, false);
    int t2lo = __builtin_amdgcn_update_dpp((int)0xFFFFFFFF, (int)(unsigned)(p2 & 0xFFFFFFFFull), CTRL, 0xF, 0xF, false);
    int t2hi = __builtin_amdgcn_update_dpp((int)0xFFFFFFFF, (int)(unsigned)(p2 >> 32), CTRL, 0xF, 0xF, false);
    u64 t1 = ((u64)(unsigned)t1hi << 32) | (unsigned)t1lo;
    u64 t2 = ((u64)(unsigned)t2hi << 32) | (unsigned)t2lo;
    if (t1 < p1) { p2 = (p1 < t2) ? p1 : t2; p1 = t1; }
    else         { p2 = (p2 < t1) ? p2 : t1; }
}

__device__ __forceinline__ int rl32(int v, int l) { return __builtin_amdgcn_readlane(v, l); }
__device__ __forceinline__ double rlf64(double v, int l) {
    int lo = __builtin_amdgcn_readlane(__double2loint(v), l);
    int hi = __builtin_amdgcn_readlane(__double2hiint(v), l);
    return __hiloint2double(hi, lo);
}
__device__ __forceinline__ u64 rlu64(u64 v, int l) {
    int lo = __builtin_amdgcn_readlane((int)(unsigned)(v & 0xFFFFFFFFull), l);
    int hi = __builtin_amdgcn_readlane((int)(unsigned)(v >> 32), l);
    return ((u64)(unsigned)hi << 32) | (unsigned)lo;
}

// ---------------------------------------------------------------------------
// Kernel 1: producers (UNCHANGED from the verified round-3 version).
// ---------------------------------------------------------------------------
struct SMC {
    float  xv[TPT * CPAD];
    float4 box[OO];
    float2 wt[OO];
    unsigned long long rmin[OO * 2];
};

__global__ __launch_bounds__(NT) void hung_cost_kernel(
    const float* __restrict__ pb, const float* __restrict__ tb,
    const float* __restrict__ cls, const int* __restrict__ tcls,
    float* __restrict__ cost, unsigned long long* __restrict__ rowmins) {
#pragma clang fp contract(off)
    __shared__ SMC sm;

    int bx = blockIdx.x;
    int b = bx & 31;
    int tile = bx >> 5;
    int t0 = tile * TPT;
    int tid = threadIdx.x;
    int lane = tid & 63;
    int wave = tid >> 6;
    int tok = tid & (TPT - 1);
    int oh = tid >> 7;

    const float* cbase = cls + ((size_t)b * TT + t0) * CC;
    #pragma unroll
    for (int k = 0; k < (TPT * CC) / (NT * 4); ++k) {
        int idx4 = (k * NT + tid) * 4;
        vf4 vv = __builtin_nontemporal_load((const vf4*)(cbase + idx4));
        int r = idx4 / CC;
        int c = idx4 - r * CC;
        float* dst = &sm.xv[r * CPAD + c];
        dst[0] = vv.x; dst[1] = vv.y; dst[2] = vv.z; dst[3] = vv.w;
    }
    if (tid < OO) {
        float4 tbox = ((const float4*)tb)[b * OO + tid];
        float x1 = tbox.x - tbox.z / 2.f;
        float y1 = tbox.y - tbox.w / 2.f;
        float x2 = tbox.x + tbox.z / 2.f;
        float y2 = tbox.y + tbox.w / 2.f;
        float4 bb; bb.x = x1; bb.y = y1; bb.z = x2; bb.w = y2;
        sm.box[tid] = bb;
        float w2 = x2 - x1;
        float h2 = (y2 - y1) + EPSF;
        float2 wt; wt.x = w2 * h2;
        wt.y = __int_as_float(tcls[b * OO + tid]);
        sm.wt[tid] = wt;
    }
    __syncthreads();

    size_t bt = (size_t)b * TT + t0 + tok;
    float4 pbox = ((const float4*)pb)[bt];
    float b1x1 = pbox.x - pbox.z / 2.f;
    float b1y1 = pbox.y - pbox.w / 2.f;
    float b1x2 = pbox.x + pbox.z / 2.f;
    float b1y2 = pbox.y + pbox.w / 2.f;
    float w1 = b1x2 - b1x1;
    float h1 = (b1y2 - b1y1) + EPSF;
    float w1h1 = w1 * h1;

    const float* xr = &sm.xv[tok * CPAD];
    float m = xr[0];
    #pragma unroll
    for (int c = 1; c < CC; ++c) m = fmaxf(m, xr[c]);
    float ssum = 0.f;
    #pragma unroll
    for (int c = 0; c < CC; ++c) ssum += expf(xr[c] - m);
    float ls = logf(ssum);

    float* cbt = cost + (size_t)b * OO * TT + t0;
    for (int k = 0; k < OO / 2; ++k) {
        int o = oh * (OO / 2) + k;
        float4 bb = sm.box[o];
        float2 wt = sm.wt[o];
        float b2x1 = bb.x, b2y1 = bb.y, b2x2 = bb.z, b2y2 = bb.w;
        float iw = fminf(b1x2, b2x2) - fmaxf(b1x1, b2x1);
        float ih = fminf(b1y2, b2y2) - fmaxf(b1y1, b2y1);
        iw = fmaxf(iw, 0.f);
        ih = fmaxf(ih, 0.f);
        float inter = iw * ih;
        float uni = ((w1h1 + wt.x) - inter) + EPSF;
        float iou = inter / uni;
        float cw = fmaxf(b1x2, b2x2) - fminf(b1x1, b2x1);
        float ch = fmaxf(b1y2, b2y2) - fminf(b1y1, b2y1);
        float c_area = (cw * ch) + EPSF;
        float giou = iou - (c_area - uni) / c_area;
        float bbox_loss = 1.0f - giou;

        float xc = xr[__float_as_int(wt.y)];
        float shifted = xc - m;
        float cls_neg = -(shifted - ls);

        float cval = bbox_loss + cls_neg;
        cbt[(size_t)o * TT + tok] = cval;

        float bvv = cval;
        int bjj = t0 + tok;
        dpp_lexmin_f32<0x111>(bvv, bjj);
        dpp_lexmin_f32<0x112>(bvv, bjj);
        dpp_lexmin_f32<0x114>(bvv, bjj);
        dpp_lexmin_f32<0x118>(bvv, bjj);
        dpp_lexmin_f32<0x142>(bvv, bjj);
        dpp_lexmin_f32<0x143>(bvv, bjj);
        if (lane == 63)
            sm.rmin[o * 2 + (wave & 1)] =
                ((unsigned long long)__float_as_uint(bvv) << 32) | (unsigned)bjj;
    }
    __syncthreads();
    if (tid < OO) {
        unsigned long long r0 = sm.rmin[tid * 2 + 0];
        unsigned long long r1 = sm.rmin[tid * 2 + 1];
        rowmins[((size_t)b * NTILE + tile) * OO + tid] = r0 < r1 ? r0 : r1;
    }
}

// ---------------------------------------------------------------------------
// Kernel 2: JV LSA, wave0-only SAP.
// Tier-1 (matched cols, slot h <-> row h) keys in wave-0 registers: no
// cross-wave exchange, no barriers in the Dijkstra loop. Tier-2 (free cols,
// v==0 until matched, never intermediate) collapses to a scalar termination
// candidate fed by a per-row top-2 free-column cache (exact, compacted on
// sink promotion, wave0 rescan fallback). Augment path walk via pop-indexed
// register chain + readlane; "writelane" expressed as per-lane cndmask
// (if (lane==idx) reg=val;) since the index is wave-uniform. Strict-< and
// lex-by-column tie-breaks preserve bit-identical selection vs the round-3
// reference loop.
// ---------------------------------------------------------------------------
struct SML {
    int    row4col[TT];          // 8 KB
    double vcol[TT];             // 16 KB  (v duals, by column)
    int    claim[TT];            // 8 KB   (greedy init only)
    u64    bf2a[OO];             // best free pack per row
    u64    bf2b[OO];             // second free pack per row
    u64    sc1[NT];              // pre-pass scratch
    u64    sc2[NT];
    unsigned bitmap[64];         // matched bitmap, 32 cols per word
    int    col4row[OO];
    double u[OO];
    int    amin[OO];
    int    flag[OO];
    int    freelist[OO];
    int    nfree;
};

__global__ __launch_bounds__(NT) void hung_lsa_kernel(
    const float* __restrict__ cost,
    const unsigned long long* __restrict__ rowmins,
    int* __restrict__ out) {
#pragma clang fp contract(off)
    __shared__ SML sm;

    int b = blockIdx.x;
    int tid = threadIdx.x;
    int lane = tid & 63;
    int wave = tid >> 6;

    const float* cb = cost + (size_t)b * OO * TT;

    // ---- Phase A: u = row minima (combine 16 tile results) ----
    if (tid < OO) {
        const unsigned long long* p = rowmins + (size_t)b * NTILE * OO + tid;
        unsigned long long best = p[0];
        #pragma unroll
        for (int t = 1; t < NTILE; ++t) {
            unsigned long long x = p[t * OO];
            if (x < best) best = x;
        }
        sm.u[tid] = (double)__uint_as_float((unsigned)(best >> 32));
        sm.amin[tid] = (int)(best & 0xFFFFFFFFull);
        sm.col4row[tid] = -1;
    }
    for (int j = tid; j < TT; j += NT) { sm.row4col[j] = -1; sm.claim[j] = 0x7FFFFFFF; }
    __syncthreads();

    // ---- Phase B: greedy tight pre-assignment (lowest row wins) ----
    if (tid < OO) atomicMin(&sm.claim[sm.amin[tid]], tid);
    __syncthreads();
    if (tid < OO) {
        int j = sm.amin[tid];
        if (sm.claim[j] == tid) { sm.col4row[tid] = j; sm.row4col[j] = tid; }
    }
    __syncthreads();

    // ---- Phase C: bf2 pre-pass (per-row top-2 FREE packs), bitmap, vcol, flags ----
    {
        int prow = tid >> 1, h = tid & 1;
        const float* rp = cb + (size_t)prow * TT + h * 1024;
        const int* mrow = &sm.row4col[h * 1024];
        u64 p1 = INVP, p2 = INVP;
        for (int k = 0; k < 1024; k += 4) {
            float4 q = *(const float4*)(rp + k);
            int4 mm = *(const int4*)(mrow + k);
            int cbase2 = h * 1024 + k;
            if (mm.x < 0) { u64 pk = ((u64)__float_as_uint(q.x) << 32) | (unsigned)(cbase2 + 0);
                            if (pk < p1) { p2 = p1; p1 = pk; } else if (pk < p2) p2 = pk; }
            if (mm.y < 0) { u64 pk = ((u64)__float_as_uint(q.y) << 32) | (unsigned)(cbase2 + 1);
                            if (pk < p1) { p2 = p1; p1 = pk; } else if (pk < p2) p2 = pk; }
            if (mm.z < 0) { u64 pk = ((u64)__float_as_uint(q.z) << 32) | (unsigned)(cbase2 + 2);
                            if (pk < p1) { p2 = p1; p1 = pk; } else if (pk < p2) p2 = pk; }
            if (mm.w < 0) { u64 pk = ((u64)__float_as_uint(q.w) << 32) | (unsigned)(cbase2 + 3);
                            if (pk < p1) { p2 = p1; p1 = pk; } else if (pk < p2) p2 = pk; }
        }
        sm.sc1[tid] = p1; sm.sc2[tid] = p2;
    }
    for (int j = tid; j < TT; j += NT) sm.vcol[j] = 0.0;
    if (tid < 64) {
        unsigned w = 0;
        for (int k = 0; k < 32; ++k) if (sm.row4col[tid * 32 + k] >= 0) w |= 1u << k;
        sm.bitmap[tid] = w;
    }
    if (tid < OO) sm.flag[tid] = (sm.col4row[tid] < 0) ? 1 : 0;
    __syncthreads();
    if (tid < OO) {
        u64 a1 = sm.sc1[2 * tid], a2 = sm.sc2[2 * tid];
        u64 b1 = sm.sc1[2 * tid + 1], b2 = sm.sc2[2 * tid + 1];
        u64 p1, p2;
        if (a1 < b1) { p1 = a1; p2 = (b1 < a2) ? b1 : a2; }
        else         { p1 = b1; p2 = (a1 < b2) ? a1 : b2; }
        sm.bf2a[tid] = p1; sm.bf2b[tid] = p2;
    }
    if (tid < OO && sm.flag[tid]) {
        int rank = 0;
        for (int o = 0; o < tid; ++o) rank += sm.flag[o];
        sm.freelist[rank] = tid;
    }
    if (tid == 0) {
        int nf = 0;
        for (int o = 0; o < OO; ++o) nf += sm.flag[o];
        sm.nfree = nf;
    }
    __syncthreads();

    if (wave != 0) return;   // waves 1-3 done; wave0 runs barrier-free below

    // ---- wave0 per-lane persistent state: slot h=lane (rows 0-63), h=lane+64 ----
    int cid0 = sm.col4row[lane];
    int cid1 = sm.col4row[lane + 64];
    double ur0 = sm.u[lane];
    double ur1 = sm.u[lane + 64];
    int rpA = 0, rpB = 0, crA = 0, crB = 0;   // rowpop / chain lane-registers
    int nfree = sm.nfree;

    for (int fi = 0; fi < nfree; ++fi) {
        int cur = sm.freelist[fi];
        double ucur = sm.u[cur];
        double key0 = INFINITY, key1 = INFINITY;
        int par0 = 0, par1 = 0;
        int popped = 0;
        double mv = 0.0, ui = ucur;
        int i = cur;
        double tc = INFINITY; int tcj = 0x7FFFFFFF; int tcpi = cur;
        int L = 0, sink, spi;

        while (true) {
            double D = ui - mv;
            bool a0 = (cid0 >= 0) && !(popped & 1);
            bool a1 = (cid1 >= 0) && !(popped & 2);
            int x0 = a0 ? cid0 : 0;
            int x1 = a1 ? cid1 : 0;
            const float* rb = cb + (size_t)i * TT;
            float cv0 = rb[x0];
            float cv1 = rb[x1];
            double vj0 = sm.vcol[x0];
            double vj1 = sm.vcol[x1];
            u64 bp = sm.bf2a[i];
            if (bp == INVP) {
                // exact rescan of row i's free columns (wave0 collective)
                unsigned fw = ~sm.bitmap[lane];
                u64 p1 = INVP, p2 = INVP;
                const float* rr = rb + lane * 32;
                for (int k = 0; k < 32; k += 4) {
                    float4 q = *(const float4*)(rr + k);
                    int cb2 = lane * 32 + k;
                    if ((fw >> (k + 0)) & 1) { u64 pk = ((u64)__float_as_uint(q.x) << 32) | (unsigned)(cb2 + 0);
                        if (pk < p1) { p2 = p1; p1 = pk; } else if (pk < p2) p2 = pk; }
                    if ((fw >> (k + 1)) & 1) { u64 pk = ((u64)__float_as_uint(q.y) << 32) | (unsigned)(cb2 + 1);
                        if (pk < p1) { p2 = p1; p1 = pk; } else if (pk < p2) p2 = pk; }
                    if ((fw >> (k + 2)) & 1) { u64 pk = ((u64)__float_as_uint(q.z) << 32) | (unsigned)(cb2 + 2);
                        if (pk < p1) { p2 = p1; p1 = pk; } else if (pk < p2) p2 = pk; }
                    if ((fw >> (k + 3)) & 1) { u64 pk = ((u64)__float_as_uint(q.w) << 32) | (unsigned)(cb2 + 3);
                        if (pk < p1) { p2 = p1; p1 = pk; } else if (pk < p2) p2 = pk; }
                }
                dpp_top2_u64<0x111>(p1, p2);
                dpp_top2_u64<0x112>(p1, p2);
                dpp_top2_u64<0x114>(p1, p2);
                dpp_top2_u64<0x118>(p1, p2);
                dpp_top2_u64<0x142>(p1, p2);
                dpp_top2_u64<0x143>(p1, p2);
                p1 = rlu64(p1, 63); p2 = rlu64(p2, 63);
                if (lane == 0) { sm.bf2a[i] = p1; sm.bf2b[i] = p2; }
                bp = p1;
            }
            // tier-2 termination candidate (lex tie-break by column)
            {
                float bfv = __uint_as_float((unsigned)(bp >> 32));
                int   bfc = (int)(bp & 0xFFFFFFFFull);
                double cnd = (double)bfv - D;      // == ((double)c - D) - 0.0
                if (cnd < tc || (cnd == tc && bfc < tcj)) { tc = cnd; tcj = bfc; tcpi = i; }
            }
            // tier-1 key updates (identical arithmetic to reference loop)
            if (a0) { double r = ((double)cv0 - D) - vj0; if (r < key0) { key0 = r; par0 = i; } }
            if (a1) { double r = ((double)cv1 - D) - vj1; if (r < key1) { key1 = r; par1 = i; } }
            // per-lane lexmin over 2 slots, then DPP to lane 63
            double bv = INFINITY; int bj = 0x7FFFFFFF;
            if (a0 && (key0 < bv || (key0 == bv && cid0 < bj))) { bv = key0; bj = cid0; }
            if (a1 && (key1 < bv || (key1 == bv && cid1 < bj))) { bv = key1; bj = cid1; }
            dpp_lexmin<0x111>(bv, bj);
            dpp_lexmin<0x112>(bv, bj);
            dpp_lexmin<0x114>(bv, bj);
            dpp_lexmin<0x118>(bv, bj);
            dpp_lexmin<0x142>(bv, bj);
            dpp_lexmin<0x143>(bv, bj);
            double MV = rlf64(bv, 63);
            int BJ = rl32(bj, 63);

            if (tc < MV || (tc == MV && tcj < BJ)) { sink = tcj; spi = tcpi; break; }

            // pop BJ (tier-1)
            mv = MV;
            unsigned long long m0 = __ballot(((popped & 1) == 0) && cid0 == BJ);
            unsigned long long m1 = __ballot(((popped & 2) == 0) && cid1 == BJ);
            int ol, os;
            if (m0) { ol = __ffsll(m0) - 1; os = 0; }
            else    { ol = __ffsll(m1) - 1; os = 1; }
            int hrow = os * 64 + ol;
            double uo = (os == 0) ? rlf64(ur0, ol) : rlf64(ur1, ol);
            int pp = (os == 0) ? rl32(par0, ol) : rl32(par1, ol);
            if (lane == ol) popped |= (os ? 2 : 1);
            int ce = (BJ << 8) | pp;                    // {col:11b, parent row:7b}
            // lane-register "writelane": indices L/hrow are wave-uniform
            if (L < 64)    { if (lane == L) crA = ce; }
            else           { if (lane == L - 64) crB = ce; }
            if (hrow < 64) { if (lane == hrow) rpA = L; }
            else           { if (lane == hrow - 64) rpB = L; }
            i = hrow; ui = uo; L++;
        }

        double M = tc;   // final mv == sink distance
        // dual updates for popped slots (delta = M - key, same as reference)
        if (popped & 1) {
            double d = M - key0; ur0 += d; sm.u[lane] = ur0;
            double vv = sm.vcol[cid0]; sm.vcol[cid0] = vv - d;
        }
        if (popped & 2) {
            double d = M - key1; ur1 += d; sm.u[lane + 64] = ur1;
            double vv = sm.vcol[cid1]; sm.vcol[cid1] = vv - d;
        }
        // augment walk (register chain + readlane; ~40 cyc/step)
        int J = sink, ii = spi;
        while (true) {
            if (lane == 0) { sm.row4col[J] = ii; sm.col4row[ii] = J; }
            bool iscur = (ii == cur);
            if (ii < 64) { if (lane == ii) { cid0 = J; if (iscur) ur0 = ucur + M; } }
            else         { if (lane == ii - 64) { cid1 = J; if (iscur) ur1 = ucur + M; } }
            if (iscur) break;
            int k = (ii < 64) ? rl32(rpA, ii) : rl32(rpB, ii - 64);
            int ce = (k < 64) ? rl32(crA, k) : rl32(crB, k - 64);
            J = ce >> 8;
            ii = ce & 0x7F;
        }
        if (lane == 0) {
            sm.u[cur] = ucur + M;
            sm.bitmap[sink >> 5] |= 1u << (sink & 31);
        }
        // bf2 compaction vs promoted sink (rows lane and lane+64)
        {
            u64 a = sm.bf2a[lane], bb2 = sm.bf2b[lane];
            if ((unsigned)(a & 0xFFFFFFFFull) == (unsigned)sink) { a = bb2; bb2 = INVP; }
            else if ((unsigned)(bb2 & 0xFFFFFFFFull) == (unsigned)sink) bb2 = INVP;
            sm.bf2a[lane] = a; sm.bf2b[lane] = bb2;
            a = sm.bf2a[lane + 64]; bb2 = sm.bf2b[lane + 64];
            if ((unsigned)(a & 0xFFFFFFFFull) == (unsigned)sink) { a = bb2; bb2 = INVP; }
            else if ((unsigned)(bb2 & 0xFFFFFFFFull) == (unsigned)sink) bb2 = INVP;
            sm.bf2a[lane + 64] = a; sm.bf2b[lane + 64] = bb2;
        }
    }

    // ---- output: order = argsort(col4row) (wave0, 2 rows per lane) ----
    #pragma unroll
    for (int h = 0; h < 2; ++h) {
        int row = lane + h * 64;
        int my = sm.col4row[row];
        int rank = 0;
        for (int o = 0; o < OO; ++o) rank += (sm.col4row[o] < my) ? 1 : 0;
        out[(size_t)b * OO + rank] = my;          // pred_idx
        out[(size_t)(BB + b) * OO + rank] = row;  // tgt_idx
    }
}

// ---------------------------------------------------------------------------
extern "C" void kernel_launch(void* const* d_in, const int* in_sizes, int n_in,
                              void* d_out, int out_size, void* d_ws, size_t ws_size,
                              hipStream_t stream) {
    const float* pred_bboxes = (const float*)d_in[0];    // [B,T,4]
    const float* target_bboxes = (const float*)d_in[1];  // [B,O,4]
    const float* pred_classes = (const float*)d_in[2];   // [B,T,C]
    const int* target_classes = (const int*)d_in[3];     // [B,O]
    int* out = (int*)d_out;                              // [2,B,O] int32

    float* cost = (float*)d_ws;  // [B][O][T] fp32 (32 MB)
    unsigned long long* rowmins =
        (unsigned long long*)(cost + (size_t)BB * OO * TT);  // [B][NTILE][O]

    hung_cost_kernel<<<BB * NTILE, NT, 0, stream>>>(
        pred_bboxes, target_bboxes, pred_classes, target_classes, cost, rowmins);
    hung_lsa_kernel<<<BB, NT, 0, stream>>>(cost, rowmins, out);
}

// Round 7
// 241.141 us; speedup vs baseline: 1.3078x; 1.3078x over previous
//
#include <hip/hip_runtime.h>
#include <math.h>
#include <float.h>

// Problem dims (fixed by setup_inputs)
#define BB 32
#define TT 2048
#define OO 128
#define CC 80
#define EPSF 1e-7f
#define NT 256
#define SLOTS 8           // columns per thread in LSA
#define CPAD 81           // LDS class-row stride: 81%32=17, gcd(17,32)=1 -> conflict-free
#define TPT 128           // tokens per cost tile
#define NTILE 16          // cost t-tiles (TT/TPT)

typedef float vf4 __attribute__((ext_vector_type(4)));   // native vec for nontemporal
typedef unsigned long long u64;

struct alignas(16) URow { double u; int row; int pad; };   // {u[row4col[j]], row4col[j]}
struct alignas(8)  P2   { int i; int j; };                 // path row, its prior column
struct alignas(16) Cand { double v; double u; int j; int row; };  // +urow folded in

// DPP lexicographic-min (val,idx): incoming lanes aggregate strictly-lower
// column ranges -> (tv <= bv) == first-index tie-break. Identity {+inf, MAX}.
template<int CTRL>
__device__ __forceinline__ void dpp_lexmin(double& bv, int& bj) {
    int lo = __double2loint(bv), hi = __double2hiint(bv);
    int tlo = __builtin_amdgcn_update_dpp(0, lo, CTRL, 0xF, 0xF, false);
    int thi = __builtin_amdgcn_update_dpp(0x7FF00000, hi, CTRL, 0xF, 0xF, false);
    int tj  = __builtin_amdgcn_update_dpp(0x7FFFFFFF, bj, CTRL, 0xF, 0xF, false);
    double tv = __hiloint2double(thi, tlo);
    if (tv <= bv) { bv = tv; bj = tj; }
}

// Packed-u64 min for the producer's rowmin: pack = (f32bits(cost)<<32) | col.
// cost >= 0 always (cls_neg >= 0, bbox_loss = 1-giou >= 0) -> f32 bits are
// monotone as unsigned -> u64 order == (value, lowest-col) lexicographic,
// identical to the old f32 (val,idx) lexmin. Identity = u64 max (never wins).
template<int CTRL>
__device__ __forceinline__ void dpp_min_u64(u64& p) {
    int tlo = __builtin_amdgcn_update_dpp((int)0xFFFFFFFF, (int)(unsigned)(p & 0xFFFFFFFFull), CTRL, 0xF, 0xF, false);
    int thi = __builtin_amdgcn_update_dpp((int)0xFFFFFFFF, (int)(unsigned)(p >> 32), CTRL, 0xF, 0xF, false);
    u64 t = ((u64)(unsigned)thi << 32) | (unsigned)tlo;
    if (t < p) p = t;
}

// ---------------------------------------------------------------------------
// Kernel 1: producers. 512 blocks, one 128-token cost tile each (2 thr/token).
// LDS = 46.5 KB -> 3 blocks/CU -> all 512 co-resident. XCD-matched mapping:
// b = bx&31 -> batch b's tiles share an XCD; cost[b] stays in that XCD's L2
// for the LSA kernel. VALU-bound (r0 fused PMC: ~80% VALUBusy for ~45us), so
// this round: (1) softmax computed ONCE per token (was 2x redundant),
// (2) packed-u64 rowmin DPP (5 instr/stage vs 7), (3) strength-reduced
// store pointer.
// ---------------------------------------------------------------------------
struct SMC {
    float  xv[TPT * CPAD];                     // 41472 B
    float4 box[OO];                            // {x1,y1,x2,y2}
    float2 wt[OO];                             // {w2h2, tc-as-float-bits}
    u64    rmin[OO * 2];                       // per-wave-half packed (m1|j1)
    float  ms[TPT];                            // per-token softmax max
    float  lsv[TPT];                           // per-token log-sum
};

__global__ __launch_bounds__(NT) void hung_cost_kernel(
    const float* __restrict__ pb, const float* __restrict__ tb,
    const float* __restrict__ cls, const int* __restrict__ tcls,
    float* __restrict__ cost, u64* __restrict__ rowmins) {
#pragma clang fp contract(off)
    __shared__ SMC sm;

    int bx = blockIdx.x;
    int b = bx & 31;
    int tile = bx >> 5;
    int t0 = tile * TPT;
    int tid = threadIdx.x;
    int lane = tid & 63;
    int wave = tid >> 6;
    int tok = tid & (TPT - 1);
    int oh = tid >> 7;           // o-half: 0 -> o in [0,64), 1 -> [64,128)

    // stage class tile (nontemporal: read-once)
    const float* cbase = cls + ((size_t)b * TT + t0) * CC;
    #pragma unroll
    for (int k = 0; k < (TPT * CC) / (NT * 4); ++k) {   // 10 iters
        int idx4 = (k * NT + tid) * 4;
        vf4 vv = __builtin_nontemporal_load((const vf4*)(cbase + idx4));
        int r = idx4 / CC;
        int c = idx4 - r * CC;
        float* dst = &sm.xv[r * CPAD + c];
        dst[0] = vv.x; dst[1] = vv.y; dst[2] = vv.z; dst[3] = vv.w;
    }
    if (tid < OO) {
        float4 tbox = ((const float4*)tb)[b * OO + tid];
        float x1 = tbox.x - tbox.z / 2.f;
        float y1 = tbox.y - tbox.w / 2.f;
        float x2 = tbox.x + tbox.z / 2.f;
        float y2 = tbox.y + tbox.w / 2.f;
        float4 bb; bb.x = x1; bb.y = y1; bb.z = x2; bb.w = y2;
        sm.box[tid] = bb;
        float w2 = x2 - x1;
        float h2 = (y2 - y1) + EPSF;
        float2 wt; wt.x = w2 * h2;
        wt.y = __int_as_float(tcls[b * OO + tid]);
        sm.wt[tid] = wt;
    }
    __syncthreads();

    // softmax normalizers, computed ONCE per token by waves 0-1 (wave-uniform
    // branch; sequential op order verbatim -> bit-identical to before/ref)
    if (tid < TPT) {
        const float* xr2 = &sm.xv[tid * CPAD];
        float m2 = xr2[0];
        #pragma unroll
        for (int c = 1; c < CC; ++c) m2 = fmaxf(m2, xr2[c]);
        float ssum = 0.f;
        #pragma unroll
        for (int c = 0; c < CC; ++c) ssum += expf(xr2[c] - m2);
        sm.ms[tid] = m2;
        sm.lsv[tid] = logf(ssum);
    }

    size_t bt = (size_t)b * TT + t0 + tok;
    float4 pbox = ((const float4*)pb)[bt];
    float b1x1 = pbox.x - pbox.z / 2.f;
    float b1y1 = pbox.y - pbox.w / 2.f;
    float b1x2 = pbox.x + pbox.z / 2.f;
    float b1y2 = pbox.y + pbox.w / 2.f;
    float w1 = b1x2 - b1x1;
    float h1 = (b1y2 - b1y1) + EPSF;
    float w1h1 = w1 * h1;
    __syncthreads();

    const float* xr = &sm.xv[tok * CPAD];
    float m = sm.ms[tok];       // 2-way LDS broadcast (free)
    float ls = sm.lsv[tok];

    float* cw = cost + (size_t)b * OO * TT + (size_t)(oh * (OO / 2)) * TT + t0 + tok;
    for (int k = 0; k < OO / 2; ++k) {
        int o = oh * (OO / 2) + k;
        float4 bb = sm.box[o];          // one b128 broadcast per wave
        float2 wt = sm.wt[o];
        float b2x1 = bb.x, b2y1 = bb.y, b2x2 = bb.z, b2y2 = bb.w;
        float iw = fminf(b1x2, b2x2) - fmaxf(b1x1, b2x1);
        float ih = fminf(b1y2, b2y2) - fmaxf(b1y1, b2y1);
        iw = fmaxf(iw, 0.f);
        ih = fmaxf(ih, 0.f);
        float inter = iw * ih;
        float uni = ((w1h1 + wt.x) - inter) + EPSF;
        float iou = inter / uni;
        float cw2 = fmaxf(b1x2, b2x2) - fminf(b1x1, b2x1);
        float ch = fmaxf(b1y2, b2y2) - fminf(b1y1, b2y1);
        float c_area = (cw2 * ch) + EPSF;
        float giou = iou - (c_area - uni) / c_area;
        float bbox_loss = 1.0f - giou;

        float xc = xr[__float_as_int(wt.y)];   // conflict-free (stride 81)
        float shifted = xc - m;
        float cls_neg = -(shifted - ls);

        float cval = bbox_loss + cls_neg;
        *cw = cval;
        cw += TT;

        // per-(b,o) wave min/argmin over this wave's 64 tokens (packed u64)
        u64 pk = ((u64)__float_as_uint(cval) << 32) | (unsigned)(t0 + tok);
        dpp_min_u64<0x111>(pk);
        dpp_min_u64<0x112>(pk);
        dpp_min_u64<0x114>(pk);
        dpp_min_u64<0x118>(pk);
        dpp_min_u64<0x142>(pk);
        dpp_min_u64<0x143>(pk);
        if (lane == 63)
            sm.rmin[o * 2 + (wave & 1)] = pk;
    }
    __syncthreads();
    if (tid < OO) {
        u64 r0 = sm.rmin[tid * 2 + 0];
        u64 r1 = sm.rmin[tid * 2 + 1];
        rowmins[((size_t)b * NTILE + tile) * OO + tid] = r0 < r1 ? r0 : r1;
    }
    // No release protocol: kernel boundary on the stream is the fence.
}

// ---------------------------------------------------------------------------
// Kernel 2: JV LSA, 32 blocks (one per batch), VERBATIM the verified
// round-3 kernel (measured 138.5 us; r4 LDS-cache and r6 wave0-SAP both
// regressed -> this 4-wave structure is near its latency floor).
// ---------------------------------------------------------------------------
struct SML {
    URow   urow[TT];
    P2     path2[TT];                          // swizzled
    int    row4col[TT];
    int    claim[TT];
    int    col4row[OO];
    double u[OO];
    int    amin[OO];
    int    flag[OO];
    int    freelist[OO];
    int    selj[OO + 8];
    double selm[OO + 8];
    int    selrow[OO + 8];
    Cand   cand[2][4];
    int    nfree;
};

__global__ __launch_bounds__(NT) void hung_lsa_kernel(
    const float* __restrict__ cost,
    const u64* __restrict__ rowmins,
    int* __restrict__ out) {
#pragma clang fp contract(off)
    __shared__ SML sm;

    int b = blockIdx.x;
    int tid = threadIdx.x;
    int lane = tid & 63;
    int wave = tid >> 6;

    const float* cb = cost + (size_t)b * OO * TT;
    const int jbase = tid * SLOTS;

    double v_[SLOTS];
    double key[SLOTS];
    #pragma unroll
    for (int s = 0; s < SLOTS; ++s) v_[s] = 0.0;

    // ---- Phase A: u = row minima (combine the 16 tile results) ----
    if (tid < OO) {
        const u64* p = rowmins + (size_t)b * NTILE * OO + tid;
        u64 best = p[0];
        #pragma unroll
        for (int t = 1; t < NTILE; ++t) {
            u64 x = p[t * OO];
            if (x < best) best = x;
        }
        sm.u[tid] = (double)__uint_as_float((unsigned)(best >> 32));
        sm.amin[tid] = (int)(best & 0xFFFFFFFFull);
        sm.col4row[tid] = -1;
    }
    for (int j = tid; j < TT; j += NT) { sm.row4col[j] = -1; sm.claim[j] = 0x7FFFFFFF; }
    __syncthreads();

    // ---- Phase B: greedy tight pre-assignment (lowest row wins) ----
    if (tid < OO) atomicMin(&sm.claim[sm.amin[tid]], tid);
    __syncthreads();
    if (tid < OO) {
        int j = sm.amin[tid];
        if (sm.claim[j] == tid) { sm.col4row[tid] = j; sm.row4col[j] = tid; }
    }
    __syncthreads();

    // ---- Phase C: urow init + free-row list ----
    for (int j = tid; j < TT; j += NT) {
        int r = sm.row4col[j];
        URow t; t.row = r; t.u = (r >= 0) ? sm.u[r] : 0.0; t.pad = 0;
        sm.urow[j] = t;
    }
    if (tid < OO) sm.flag[tid] = (sm.col4row[tid] < 0) ? 1 : 0;
    __syncthreads();
    if (tid < OO && sm.flag[tid]) {
        int rank = 0;
        for (int o = 0; o < tid; ++o) rank += sm.flag[o];
        sm.freelist[rank] = tid;
    }
    if (tid == 0) {
        int nf = 0;
        for (int o = 0; o < OO; ++o) nf += sm.flag[o];
        sm.nfree = nf;
    }
    __syncthreads();
    int nfree = sm.nfree;

    // root-row prefetch for the first Dijkstra
    float4 pf0, pf1;
    if (nfree > 0) {
        const float* rr = cb + (size_t)sm.freelist[0] * TT + jbase;
        pf0 = *(const float4*)rr;
        pf1 = *(const float4*)(rr + 4);
    }

    // ---- Phase D: Dijkstra SAP ----
    int par = 0;
    for (int fi = 0; fi < nfree; ++fi) {
        int cur = sm.freelist[fi];

        #pragma unroll
        for (int s = 0; s < SLOTS; ++s) key[s] = INFINITY;
        int selbits = 0;
        double mv = 0.0;
        int i = cur, jc = -1;
        double ui = sm.u[cur];
        float4 c0 = pf0, c1 = pf1;
        int L = 0, sink;

        while (true) {
            float cv[SLOTS] = {c0.x, c0.y, c0.z, c0.w, c1.x, c1.y, c1.z, c1.w};
            double D = ui - mv;   // wave-uniform; one dependent op hoisted

            double bv = INFINITY;
            int bj = TT;
            #pragma unroll
            for (int s = 0; s < SLOTS; ++s) {
                if (!((selbits >> s) & 1)) {
                    double r = ((double)cv[s] - D) - v_[s];
                    if (r < key[s]) {
                        key[s] = r;
                        P2 p; p.i = i; p.j = jc;
                        sm.path2[s * NT + tid] = p;
                    }
                    double kk = key[s];
                    if (kk < bv) { bv = kk; bj = jbase + s; }
                }
            }
            dpp_lexmin<0x111>(bv, bj);
            dpp_lexmin<0x112>(bv, bj);
            dpp_lexmin<0x114>(bv, bj);
            dpp_lexmin<0x118>(bv, bj);
            dpp_lexmin<0x142>(bv, bj);
            dpp_lexmin<0x143>(bv, bj);
            int rlo = __builtin_amdgcn_readlane(__double2loint(bv), 63);
            int rhi = __builtin_amdgcn_readlane(__double2hiint(bv), 63);
            double wv = __hiloint2double(rhi, rlo);
            int wj = __builtin_amdgcn_readlane(bj, 63);

            // Pre-barrier urow fold-in: each wave reads its own candidate's
            // urow entry (read-only during the while loop); the LDS latency
            // overlaps other waves' barrier arrival.
            URow uwv = sm.urow[wj];            // wave-uniform b128 read

            par ^= 1;
            if (lane == 0) {
                Cand c; c.v = wv; c.u = uwv.u; c.j = wj; c.row = uwv.row;
                sm.cand[par][wave] = c;
            }
            __syncthreads();

            Cand cc0 = sm.cand[par][0];
            Cand cc1 = sm.cand[par][1];
            Cand cc2 = sm.cand[par][2];
            Cand cc3 = sm.cand[par][3];
            double MV = cc0.v; int BJ = cc0.j; int WR = cc0.row; double WU = cc0.u;
            if (cc1.v < MV || (cc1.v == MV && cc1.j < BJ)) { MV = cc1.v; BJ = cc1.j; WR = cc1.row; WU = cc1.u; }
            if (cc2.v < MV || (cc2.v == MV && cc2.j < BJ)) { MV = cc2.v; BJ = cc2.j; WR = cc2.row; WU = cc2.u; }
            if (cc3.v < MV || (cc3.v == MV && cc3.j < BJ)) { MV = cc3.v; BJ = cc3.j; WR = cc3.row; WU = cc3.u; }
            mv = MV;
            if ((BJ >> 3) == tid) selbits |= 1 << (BJ & 7);
            if (tid == 0) sm.selj[L] = BJ;

            if (WR < 0) { sink = BJ; break; }
            if (tid == 0) { sm.selm[L] = MV; sm.selrow[L] = WR; }
            i = WR; ui = WU; jc = BJ;
            L++;
            const float* crow = cb + (size_t)i * TT + jbase;
            c0 = *(const float4*)crow;
            c1 = *(const float4*)(crow + 4);
        }

        // prefetch next Dijkstra's root row (off the critical path)
        if (fi + 1 < nfree) {
            const float* rr = cb + (size_t)sm.freelist[fi + 1] * TT + jbase;
            pf0 = *(const float4*)rr;
            pf1 = *(const float4*)(rr + 4);
        }

        double M = mv;
        #pragma unroll
        for (int s = 0; s < SLOTS; ++s)
            if ((selbits >> s) & 1) v_[s] = v_[s] - (M - key[s]);
        for (int k = tid; k < L; k += NT)
            sm.u[sm.selrow[k]] = sm.u[sm.selrow[k]] + (M - sm.selm[k]);
        if (tid == 0) {
            sm.u[cur] = sm.u[cur] + M;
            int j = sink;
            while (true) {
                P2 p = sm.path2[(j & 7) * NT + (j >> 3)];
                int ii = p.i;
                sm.row4col[j] = ii;
                sm.col4row[ii] = j;
                if (ii == cur) break;
                j = p.j;
            }
        }
        __syncthreads();
        if (tid <= L) {
            int j = sm.selj[tid];
            int r = sm.row4col[j];
            URow t; t.u = sm.u[r]; t.row = r; t.pad = 0;
            sm.urow[j] = t;
        }
        __syncthreads();
    }

    // order = argsort(col4row); pred_idx = col4row[order]; tgt_idx = order
    if (tid < OO) {
        int my = sm.col4row[tid];
        int rank = 0;
        for (int o = 0; o < OO; ++o) rank += (sm.col4row[o] < my) ? 1 : 0;
        out[(size_t)b * OO + rank] = my;         // pred_idx
        out[(size_t)(BB + b) * OO + rank] = tid; // tgt_idx
    }
}

// ---------------------------------------------------------------------------
extern "C" void kernel_launch(void* const* d_in, const int* in_sizes, int n_in,
                              void* d_out, int out_size, void* d_ws, size_t ws_size,
                              hipStream_t stream) {
    const float* pred_bboxes = (const float*)d_in[0];    // [B,T,4]
    const float* target_bboxes = (const float*)d_in[1];  // [B,O,4]
    const float* pred_classes = (const float*)d_in[2];   // [B,T,C]
    const int* target_classes = (const int*)d_in[3];     // [B,O]
    int* out = (int*)d_out;                              // [2,B,O] int32

    float* cost = (float*)d_ws;  // [B][O][T] fp32 (32 MB)
    u64* rowmins = (u64*)(cost + (size_t)BB * OO * TT);  // [B][NTILE][O]

    hung_cost_kernel<<<BB * NTILE, NT, 0, stream>>>(
        pred_bboxes, target_bboxes, pred_classes, target_classes, cost, rowmins);
    hung_lsa_kernel<<<BB, NT, 0, stream>>>(cost, rowmins, out);
}

// Round 8
// 239.293 us; speedup vs baseline: 1.3179x; 1.0077x over previous
//
#include <hip/hip_runtime.h>
#include <math.h>
#include <float.h>

// Problem dims (fixed by setup_inputs)
#define BB 32
#define TT 2048
#define OO 128
#define CC 80
#define EPSF 1e-7f
#define NT 256
#define SLOTS 8           // columns per thread in LSA
#define CPAD 81           // LDS class-row stride: 81%32=17, gcd(17,32)=1 -> conflict-free
#define TPT 128           // tokens per cost tile
#define NTILE 16          // cost t-tiles (TT/TPT)

typedef float vf4 __attribute__((ext_vector_type(4)));   // native vec for nontemporal
typedef unsigned long long u64;

struct alignas(16) URow { double u; int row; int pad; };   // {u[row4col[j]], row4col[j]}
struct alignas(8)  P2   { int i; int j; };                 // path row, its prior column
struct alignas(16) Cand { double v; double u; int j; int row; };  // +urow folded in

// DPP lexicographic-min (val,idx): incoming lanes aggregate strictly-lower
// column ranges -> (tv <= bv) == first-index tie-break. Identity {+inf, MAX}.
template<int CTRL>
__device__ __forceinline__ void dpp_lexmin(double& bv, int& bj) {
    int lo = __double2loint(bv), hi = __double2hiint(bv);
    int tlo = __builtin_amdgcn_update_dpp(0, lo, CTRL, 0xF, 0xF, false);
    int thi = __builtin_amdgcn_update_dpp(0x7FF00000, hi, CTRL, 0xF, 0xF, false);
    int tj  = __builtin_amdgcn_update_dpp(0x7FFFFFFF, bj, CTRL, 0xF, 0xF, false);
    double tv = __hiloint2double(thi, tlo);
    if (tv <= bv) { bv = tv; bj = tj; }
}

// f32 wave-min step: 2 instr/stage (update_dpp + v_min_f32). Identity +INF.
template<int CTRL>
__device__ __forceinline__ float dpp_minf(float v) {
    int t = __builtin_amdgcn_update_dpp(0x7F800000, __float_as_int(v), CTRL, 0xF, 0xF, false);
    return fminf(v, __int_as_float(t));
}

// ---------------------------------------------------------------------------
// Kernel 1: producers. 512 blocks, one 128-token cost tile each (2 thr/token).
// LDS = 46.5 KB -> 3 blocks/CU -> all 512 co-resident. XCD-matched mapping:
// b = bx&31 -> batch b's tiles share an XCD; cost[b] stays in that XCD's L2
// for the LSA kernel. This round: rowmin reduction via f32 fminf-DPP (6x2
// instr) + readlane + ballot argmin (~18 instr/iter vs 30 for the packed-u64
// chain). Emitted (m1|j1) pack is bit-identical: f32-bits-as-unsigned order
// == float order on non-negative costs, and lowest ballot lane == lowest
// column (col = t0 + (wave&1)*64 + lane is monotone in lane).
// ---------------------------------------------------------------------------
struct SMC {
    float  xv[TPT * CPAD];                     // 41472 B
    float4 box[OO];                            // {x1,y1,x2,y2}
    float2 wt[OO];                             // {w2h2, tc-as-float-bits}
    u64    rmin[OO * 2];                       // per-wave-half packed (m1|j1)
    float  ms[TPT];                            // per-token softmax max
    float  lsv[TPT];                           // per-token log-sum
};

__global__ __launch_bounds__(NT) void hung_cost_kernel(
    const float* __restrict__ pb, const float* __restrict__ tb,
    const float* __restrict__ cls, const int* __restrict__ tcls,
    float* __restrict__ cost, u64* __restrict__ rowmins) {
#pragma clang fp contract(off)
    __shared__ SMC sm;

    int bx = blockIdx.x;
    int b = bx & 31;
    int tile = bx >> 5;
    int t0 = tile * TPT;
    int tid = threadIdx.x;
    int lane = tid & 63;
    int wave = tid >> 6;
    int tok = tid & (TPT - 1);
    int oh = tid >> 7;           // o-half: 0 -> o in [0,64), 1 -> [64,128)

    // stage class tile (nontemporal: read-once)
    const float* cbase = cls + ((size_t)b * TT + t0) * CC;
    #pragma unroll
    for (int k = 0; k < (TPT * CC) / (NT * 4); ++k) {   // 10 iters
        int idx4 = (k * NT + tid) * 4;
        vf4 vv = __builtin_nontemporal_load((const vf4*)(cbase + idx4));
        int r = idx4 / CC;
        int c = idx4 - r * CC;
        float* dst = &sm.xv[r * CPAD + c];
        dst[0] = vv.x; dst[1] = vv.y; dst[2] = vv.z; dst[3] = vv.w;
    }
    if (tid < OO) {
        float4 tbox = ((const float4*)tb)[b * OO + tid];
        float x1 = tbox.x - tbox.z / 2.f;
        float y1 = tbox.y - tbox.w / 2.f;
        float x2 = tbox.x + tbox.z / 2.f;
        float y2 = tbox.y + tbox.w / 2.f;
        float4 bb; bb.x = x1; bb.y = y1; bb.z = x2; bb.w = y2;
        sm.box[tid] = bb;
        float w2 = x2 - x1;
        float h2 = (y2 - y1) + EPSF;
        float2 wt; wt.x = w2 * h2;
        wt.y = __int_as_float(tcls[b * OO + tid]);
        sm.wt[tid] = wt;
    }
    __syncthreads();

    // softmax normalizers, computed ONCE per token by waves 0-1 (wave-uniform
    // branch; sequential op order verbatim -> bit-identical to ref)
    if (tid < TPT) {
        const float* xr2 = &sm.xv[tid * CPAD];
        float m2 = xr2[0];
        #pragma unroll
        for (int c = 1; c < CC; ++c) m2 = fmaxf(m2, xr2[c]);
        float ssum = 0.f;
        #pragma unroll
        for (int c = 0; c < CC; ++c) ssum += expf(xr2[c] - m2);
        sm.ms[tid] = m2;
        sm.lsv[tid] = logf(ssum);
    }

    size_t bt = (size_t)b * TT + t0 + tok;
    float4 pbox = ((const float4*)pb)[bt];
    float b1x1 = pbox.x - pbox.z / 2.f;
    float b1y1 = pbox.y - pbox.w / 2.f;
    float b1x2 = pbox.x + pbox.z / 2.f;
    float b1y2 = pbox.y + pbox.w / 2.f;
    float w1 = b1x2 - b1x1;
    float h1 = (b1y2 - b1y1) + EPSF;
    float w1h1 = w1 * h1;
    __syncthreads();

    const float* xr = &sm.xv[tok * CPAD];
    float m = sm.ms[tok];       // 2-way LDS broadcast (free)
    float ls = sm.lsv[tok];

    int colbase = t0 + ((wave & 1) << 6);   // this wave's token base
    float* cw = cost + (size_t)b * OO * TT + (size_t)(oh * (OO / 2)) * TT + t0 + tok;
    for (int k = 0; k < OO / 2; ++k) {
        int o = oh * (OO / 2) + k;
        float4 bb = sm.box[o];          // one b128 broadcast per wave
        float2 wt = sm.wt[o];
        float b2x1 = bb.x, b2y1 = bb.y, b2x2 = bb.z, b2y2 = bb.w;
        float iw = fminf(b1x2, b2x2) - fmaxf(b1x1, b2x1);
        float ih = fminf(b1y2, b2y2) - fmaxf(b1y1, b2y1);
        iw = fmaxf(iw, 0.f);
        ih = fmaxf(ih, 0.f);
        float inter = iw * ih;
        float uni = ((w1h1 + wt.x) - inter) + EPSF;
        float iou = inter / uni;
        float cw2 = fmaxf(b1x2, b2x2) - fminf(b1x1, b2x1);
        float ch = fmaxf(b1y2, b2y2) - fminf(b1y1, b2y1);
        float c_area = (cw2 * ch) + EPSF;
        float giou = iou - (c_area - uni) / c_area;
        float bbox_loss = 1.0f - giou;

        float xc = xr[__float_as_int(wt.y)];   // conflict-free (stride 81)
        float shifted = xc - m;
        float cls_neg = -(shifted - ls);

        float cval = bbox_loss + cls_neg;
        *cw = cval;
        cw += TT;

        // wave min via f32 fminf-DPP, argmin via ballot (lowest lane = lowest col)
        float bvv = cval;
        bvv = dpp_minf<0x111>(bvv);
        bvv = dpp_minf<0x112>(bvv);
        bvv = dpp_minf<0x114>(bvv);
        bvv = dpp_minf<0x118>(bvv);
        bvv = dpp_minf<0x142>(bvv);
        bvv = dpp_minf<0x143>(bvv);
        float mv = __int_as_float(__builtin_amdgcn_readlane(__float_as_int(bvv), 63));
        unsigned long long msk = __ballot(cval == mv);
        int col = colbase + (__ffsll((long long)msk) - 1);
        if (lane == 63)
            sm.rmin[o * 2 + (wave & 1)] =
                ((u64)__float_as_uint(mv) << 32) | (unsigned)col;
    }
    __syncthreads();
    if (tid < OO) {
        u64 r0 = sm.rmin[tid * 2 + 0];
        u64 r1 = sm.rmin[tid * 2 + 1];
        rowmins[((size_t)b * NTILE + tile) * OO + tid] = r0 < r1 ? r0 : r1;
    }
    // No release protocol: kernel boundary on the stream is the fence.
}

// ---------------------------------------------------------------------------
// Kernel 2: JV LSA, 32 blocks (one per batch), VERBATIM the verified
// round-3/7 kernel (measured 138.5-139 us; r4 LDS-cache, r6 wave0-SAP and
// r2 auction all regressed -> this 4-wave structure is at its latency floor).
// ---------------------------------------------------------------------------
struct SML {
    URow   urow[TT];
    P2     path2[TT];                          // swizzled
    int    row4col[TT];
    int    claim[TT];
    int    col4row[OO];
    double u[OO];
    int    amin[OO];
    int    flag[OO];
    int    freelist[OO];
    int    selj[OO + 8];
    double selm[OO + 8];
    int    selrow[OO + 8];
    Cand   cand[2][4];
    int    nfree;
};

__global__ __launch_bounds__(NT) void hung_lsa_kernel(
    const float* __restrict__ cost,
    const u64* __restrict__ rowmins,
    int* __restrict__ out) {
#pragma clang fp contract(off)
    __shared__ SML sm;

    int b = blockIdx.x;
    int tid = threadIdx.x;
    int lane = tid & 63;
    int wave = tid >> 6;

    const float* cb = cost + (size_t)b * OO * TT;
    const int jbase = tid * SLOTS;

    double v_[SLOTS];
    double key[SLOTS];
    #pragma unroll
    for (int s = 0; s < SLOTS; ++s) v_[s] = 0.0;

    // ---- Phase A: u = row minima (combine the 16 tile results) ----
    if (tid < OO) {
        const u64* p = rowmins + (size_t)b * NTILE * OO + tid;
        u64 best = p[0];
        #pragma unroll
        for (int t = 1; t < NTILE; ++t) {
            u64 x = p[t * OO];
            if (x < best) best = x;
        }
        sm.u[tid] = (double)__uint_as_float((unsigned)(best >> 32));
        sm.amin[tid] = (int)(best & 0xFFFFFFFFull);
        sm.col4row[tid] = -1;
    }
    for (int j = tid; j < TT; j += NT) { sm.row4col[j] = -1; sm.claim[j] = 0x7FFFFFFF; }
    __syncthreads();

    // ---- Phase B: greedy tight pre-assignment (lowest row wins) ----
    if (tid < OO) atomicMin(&sm.claim[sm.amin[tid]], tid);
    __syncthreads();
    if (tid < OO) {
        int j = sm.amin[tid];
        if (sm.claim[j] == tid) { sm.col4row[tid] = j; sm.row4col[j] = tid; }
    }
    __syncthreads();

    // ---- Phase C: urow init + free-row list ----
    for (int j = tid; j < TT; j += NT) {
        int r = sm.row4col[j];
        URow t; t.row = r; t.u = (r >= 0) ? sm.u[r] : 0.0; t.pad = 0;
        sm.urow[j] = t;
    }
    if (tid < OO) sm.flag[tid] = (sm.col4row[tid] < 0) ? 1 : 0;
    __syncthreads();
    if (tid < OO && sm.flag[tid]) {
        int rank = 0;
        for (int o = 0; o < tid; ++o) rank += sm.flag[o];
        sm.freelist[rank] = tid;
    }
    if (tid == 0) {
        int nf = 0;
        for (int o = 0; o < OO; ++o) nf += sm.flag[o];
        sm.nfree = nf;
    }
    __syncthreads();
    int nfree = sm.nfree;

    // root-row prefetch for the first Dijkstra
    float4 pf0, pf1;
    if (nfree > 0) {
        const float* rr = cb + (size_t)sm.freelist[0] * TT + jbase;
        pf0 = *(const float4*)rr;
        pf1 = *(const float4*)(rr + 4);
    }

    // ---- Phase D: Dijkstra SAP ----
    int par = 0;
    for (int fi = 0; fi < nfree; ++fi) {
        int cur = sm.freelist[fi];

        #pragma unroll
        for (int s = 0; s < SLOTS; ++s) key[s] = INFINITY;
        int selbits = 0;
        double mv = 0.0;
        int i = cur, jc = -1;
        double ui = sm.u[cur];
        float4 c0 = pf0, c1 = pf1;
        int L = 0, sink;

        while (true) {
            float cv[SLOTS] = {c0.x, c0.y, c0.z, c0.w, c1.x, c1.y, c1.z, c1.w};
            double D = ui - mv;   // wave-uniform; one dependent op hoisted

            double bv = INFINITY;
            int bj = TT;
            #pragma unroll
            for (int s = 0; s < SLOTS; ++s) {
                if (!((selbits >> s) & 1)) {
                    double r = ((double)cv[s] - D) - v_[s];
                    if (r < key[s]) {
                        key[s] = r;
                        P2 p; p.i = i; p.j = jc;
                        sm.path2[s * NT + tid] = p;
                    }
                    double kk = key[s];
                    if (kk < bv) { bv = kk; bj = jbase + s; }
                }
            }
            dpp_lexmin<0x111>(bv, bj);
            dpp_lexmin<0x112>(bv, bj);
            dpp_lexmin<0x114>(bv, bj);
            dpp_lexmin<0x118>(bv, bj);
            dpp_lexmin<0x142>(bv, bj);
            dpp_lexmin<0x143>(bv, bj);
            int rlo = __builtin_amdgcn_readlane(__double2loint(bv), 63);
            int rhi = __builtin_amdgcn_readlane(__double2hiint(bv), 63);
            double wv = __hiloint2double(rhi, rlo);
            int wj = __builtin_amdgcn_readlane(bj, 63);

            // Pre-barrier urow fold-in: each wave reads its own candidate's
            // urow entry (read-only during the while loop); the LDS latency
            // overlaps other waves' barrier arrival.
            URow uwv = sm.urow[wj];            // wave-uniform b128 read

            par ^= 1;
            if (lane == 0) {
                Cand c; c.v = wv; c.u = uwv.u; c.j = wj; c.row = uwv.row;
                sm.cand[par][wave] = c;
            }
            __syncthreads();

            Cand cc0 = sm.cand[par][0];
            Cand cc1 = sm.cand[par][1];
            Cand cc2 = sm.cand[par][2];
            Cand cc3 = sm.cand[par][3];
            double MV = cc0.v; int BJ = cc0.j; int WR = cc0.row; double WU = cc0.u;
            if (cc1.v < MV || (cc1.v == MV && cc1.j < BJ)) { MV = cc1.v; BJ = cc1.j; WR = cc1.row; WU = cc1.u; }
            if (cc2.v < MV || (cc2.v == MV && cc2.j < BJ)) { MV = cc2.v; BJ = cc2.j; WR = cc2.row; WU = cc2.u; }
            if (cc3.v < MV || (cc3.v == MV && cc3.j < BJ)) { MV = cc3.v; BJ = cc3.j; WR = cc3.row; WU = cc3.u; }
            mv = MV;
            if ((BJ >> 3) == tid) selbits |= 1 << (BJ & 7);
            if (tid == 0) sm.selj[L] = BJ;

            if (WR < 0) { sink = BJ; break; }
            if (tid == 0) { sm.selm[L] = MV; sm.selrow[L] = WR; }
            i = WR; ui = WU; jc = BJ;
            L++;
            const float* crow = cb + (size_t)i * TT + jbase;
            c0 = *(const float4*)crow;
            c1 = *(const float4*)(crow + 4);
        }

        // prefetch next Dijkstra's root row (off the critical path)
        if (fi + 1 < nfree) {
            const float* rr = cb + (size_t)sm.freelist[fi + 1] * TT + jbase;
            pf0 = *(const float4*)rr;
            pf1 = *(const float4*)(rr + 4);
        }

        double M = mv;
        #pragma unroll
        for (int s = 0; s < SLOTS; ++s)
            if ((selbits >> s) & 1) v_[s] = v_[s] - (M - key[s]);
        for (int k = tid; k < L; k += NT)
            sm.u[sm.selrow[k]] = sm.u[sm.selrow[k]] + (M - sm.selm[k]);
        if (tid == 0) {
            sm.u[cur] = sm.u[cur] + M;
            int j = sink;
            while (true) {
                P2 p = sm.path2[(j & 7) * NT + (j >> 3)];
                int ii = p.i;
                sm.row4col[j] = ii;
                sm.col4row[ii] = j;
                if (ii == cur) break;
                j = p.j;
            }
        }
        __syncthreads();
        if (tid <= L) {
            int j = sm.selj[tid];
            int r = sm.row4col[j];
            URow t; t.u = sm.u[r]; t.row = r; t.pad = 0;
            sm.urow[j] = t;
        }
        __syncthreads();
    }

    // order = argsort(col4row); pred_idx = col4row[order]; tgt_idx = order
    if (tid < OO) {
        int my = sm.col4row[tid];
        int rank = 0;
        for (int o = 0; o < OO; ++o) rank += (sm.col4row[o] < my) ? 1 : 0;
        out[(size_t)b * OO + rank] = my;         // pred_idx
        out[(size_t)(BB + b) * OO + rank] = tid; // tgt_idx
    }
}

// ---------------------------------------------------------------------------
extern "C" void kernel_launch(void* const* d_in, const int* in_sizes, int n_in,
                              void* d_out, int out_size, void* d_ws, size_t ws_size,
                              hipStream_t stream) {
    const float* pred_bboxes = (const float*)d_in[0];    // [B,T,4]
    const float* target_bboxes = (const float*)d_in[1];  // [B,O,4]
    const float* pred_classes = (const float*)d_in[2];   // [B,T,C]
    const int* target_classes = (const int*)d_in[3];     // [B,O]
    int* out = (int*)d_out;                              // [2,B,O] int32

    float* cost = (float*)d_ws;  // [B][O][T] fp32 (32 MB)
    u64* rowmins = (u64*)(cost + (size_t)BB * OO * TT);  // [B][NTILE][O]

    hung_cost_kernel<<<BB * NTILE, NT, 0, stream>>>(
        pred_bboxes, target_bboxes, pred_classes, target_classes, cost, rowmins);
    hung_lsa_kernel<<<BB, NT, 0, stream>>>(cost, rowmins, out);
}

// Round 9
// 234.589 us; speedup vs baseline: 1.3443x; 1.0201x over previous
//
#include <hip/hip_runtime.h>
#include <math.h>
#include <float.h>

// Problem dims (fixed by setup_inputs)
#define BB 32
#define TT 2048
#define OO 128
#define CC 80
#define EPSF 1e-7f
#define NT 256            // LSA block size
#define NTP 512           // producer block size (4 thr/token -> 4 waves/SIMD)
#define SLOTS 8           // columns per thread in LSA
#define CPAD 81           // LDS class-row stride: 81%32=17, gcd(17,32)=1 -> conflict-free
#define TPT 128           // tokens per cost tile
#define NTILE 16          // cost t-tiles (TT/TPT)

typedef float vf4 __attribute__((ext_vector_type(4)));   // native vec for nontemporal
typedef unsigned long long u64;

struct alignas(16) URow { double u; int row; int pad; };   // {u[row4col[j]], row4col[j]}
struct alignas(8)  P2   { int i; int j; };                 // path row, its prior column
struct alignas(16) Cand { double v; double u; int j; int row; };  // +urow folded in

// DPP lexicographic-min (val,idx): incoming lanes aggregate strictly-lower
// column ranges -> (tv <= bv) == first-index tie-break. Identity {+inf, MAX}.
template<int CTRL>
__device__ __forceinline__ void dpp_lexmin(double& bv, int& bj) {
    int lo = __double2loint(bv), hi = __double2hiint(bv);
    int tlo = __builtin_amdgcn_update_dpp(0, lo, CTRL, 0xF, 0xF, false);
    int thi = __builtin_amdgcn_update_dpp(0x7FF00000, hi, CTRL, 0xF, 0xF, false);
    int tj  = __builtin_amdgcn_update_dpp(0x7FFFFFFF, bj, CTRL, 0xF, 0xF, false);
    double tv = __hiloint2double(thi, tlo);
    if (tv <= bv) { bv = tv; bj = tj; }
}

// f32 wave-min step: 2 instr/stage (update_dpp + v_min_f32). Identity +INF.
template<int CTRL>
__device__ __forceinline__ float dpp_minf(float v) {
    int t = __builtin_amdgcn_update_dpp(0x7F800000, __float_as_int(v), CTRL, 0xF, 0xF, false);
    return fminf(v, __int_as_float(t));
}

// ---------------------------------------------------------------------------
// Kernel 1: producers. 512 blocks x 512 threads, one 128-token cost tile per
// block, 4 threads/token (o-quarters), 32-iter cost loop. Same 46.5 KB LDS ->
// 2 blocks/CU -> 8 waves/SIMD-pair... net 4 waves/SIMD resident (was 2 at
// NT=256): the producer is latency-bound (r8: instruction trims gained only
// 1.8us), so doubling resident waves halves stall exposure. Wave w covers
// token-half (w&1) and o-quarter (w>>1); per-o partials rmin[o*2+(w&1)] and
// the combine are BIT-IDENTICAL to r8 -> rowmins layout/content unchanged ->
// LSA kernel untouched. XCD mapping: b = bx&31 keeps batch b's tiles and its
// LSA block on one XCD.
// ---------------------------------------------------------------------------
struct SMC {
    float  xv[TPT * CPAD];                     // 41472 B
    float4 box[OO];                            // {x1,y1,x2,y2}
    float2 wt[OO];                             // {w2h2, tc-as-float-bits}
    u64    rmin[OO * 2];                       // per-token-half packed (m1|j1)
    float  ms[TPT];                            // per-token softmax max
    float  lsv[TPT];                           // per-token log-sum
};

__global__ __launch_bounds__(NTP) void hung_cost_kernel(
    const float* __restrict__ pb, const float* __restrict__ tb,
    const float* __restrict__ cls, const int* __restrict__ tcls,
    float* __restrict__ cost, u64* __restrict__ rowmins) {
#pragma clang fp contract(off)
    __shared__ SMC sm;

    int bx = blockIdx.x;
    int b = bx & 31;
    int tile = bx >> 5;
    int t0 = tile * TPT;
    int tid = threadIdx.x;
    int lane = tid & 63;
    int wave = tid >> 6;         // 0..7
    int tok = tid & (TPT - 1);   // token: wave&1 selects half, lane selects slot
    int oq = tid >> 7;           // o-quarter: o in [oq*32, oq*32+32)

    // stage class tile (nontemporal: read-once)
    const float* cbase = cls + ((size_t)b * TT + t0) * CC;
    #pragma unroll
    for (int k = 0; k < (TPT * CC) / (NTP * 4); ++k) {   // 5 iters
        int idx4 = (k * NTP + tid) * 4;
        vf4 vv = __builtin_nontemporal_load((const vf4*)(cbase + idx4));
        int r = idx4 / CC;
        int c = idx4 - r * CC;
        float* dst = &sm.xv[r * CPAD + c];
        dst[0] = vv.x; dst[1] = vv.y; dst[2] = vv.z; dst[3] = vv.w;
    }
    if (tid < OO) {
        float4 tbox = ((const float4*)tb)[b * OO + tid];
        float x1 = tbox.x - tbox.z / 2.f;
        float y1 = tbox.y - tbox.w / 2.f;
        float x2 = tbox.x + tbox.z / 2.f;
        float y2 = tbox.y + tbox.w / 2.f;
        float4 bb; bb.x = x1; bb.y = y1; bb.z = x2; bb.w = y2;
        sm.box[tid] = bb;
        float w2 = x2 - x1;
        float h2 = (y2 - y1) + EPSF;
        float2 wt; wt.x = w2 * h2;
        wt.y = __int_as_float(tcls[b * OO + tid]);
        sm.wt[tid] = wt;
    }
    __syncthreads();

    // softmax normalizers, ONCE per token (threads 0-127; sequential op order
    // verbatim -> bit-identical to ref)
    if (tid < TPT) {
        const float* xr2 = &sm.xv[tid * CPAD];
        float m2 = xr2[0];
        #pragma unroll
        for (int c = 1; c < CC; ++c) m2 = fmaxf(m2, xr2[c]);
        float ssum = 0.f;
        #pragma unroll
        for (int c = 0; c < CC; ++c) ssum += expf(xr2[c] - m2);
        sm.ms[tid] = m2;
        sm.lsv[tid] = logf(ssum);
    }

    size_t bt = (size_t)b * TT + t0 + tok;
    float4 pbox = ((const float4*)pb)[bt];
    float b1x1 = pbox.x - pbox.z / 2.f;
    float b1y1 = pbox.y - pbox.w / 2.f;
    float b1x2 = pbox.x + pbox.z / 2.f;
    float b1y2 = pbox.y + pbox.w / 2.f;
    float w1 = b1x2 - b1x1;
    float h1 = (b1y2 - b1y1) + EPSF;
    float w1h1 = w1 * h1;
    __syncthreads();

    const float* xr = &sm.xv[tok * CPAD];
    float m = sm.ms[tok];       // 4-way LDS broadcast (free)
    float ls = sm.lsv[tok];

    int colbase = t0 + ((wave & 1) << 6);   // this wave's token base
    float* cw = cost + (size_t)b * OO * TT + (size_t)(oq * (OO / 4)) * TT + t0 + tok;
    for (int k = 0; k < OO / 4; ++k) {      // 32 iters
        int o = oq * (OO / 4) + k;
        float4 bb = sm.box[o];          // one b128 broadcast per wave
        float2 wt = sm.wt[o];
        float b2x1 = bb.x, b2y1 = bb.y, b2x2 = bb.z, b2y2 = bb.w;
        float iw = fminf(b1x2, b2x2) - fmaxf(b1x1, b2x1);
        float ih = fminf(b1y2, b2y2) - fmaxf(b1y1, b2y1);
        iw = fmaxf(iw, 0.f);
        ih = fmaxf(ih, 0.f);
        float inter = iw * ih;
        float uni = ((w1h1 + wt.x) - inter) + EPSF;
        float iou = inter / uni;
        float cw2 = fmaxf(b1x2, b2x2) - fminf(b1x1, b2x1);
        float ch = fmaxf(b1y2, b2y2) - fminf(b1y1, b2y1);
        float c_area = (cw2 * ch) + EPSF;
        float giou = iou - (c_area - uni) / c_area;
        float bbox_loss = 1.0f - giou;

        float xc = xr[__float_as_int(wt.y)];   // conflict-free (stride 81)
        float shifted = xc - m;
        float cls_neg = -(shifted - ls);

        float cval = bbox_loss + cls_neg;
        *cw = cval;
        cw += TT;

        // wave min via f32 fminf-DPP, argmin via ballot (lowest lane = lowest col)
        float bvv = cval;
        bvv = dpp_minf<0x111>(bvv);
        bvv = dpp_minf<0x112>(bvv);
        bvv = dpp_minf<0x114>(bvv);
        bvv = dpp_minf<0x118>(bvv);
        bvv = dpp_minf<0x142>(bvv);
        bvv = dpp_minf<0x143>(bvv);
        float mv = __int_as_float(__builtin_amdgcn_readlane(__float_as_int(bvv), 63));
        unsigned long long msk = __ballot(cval == mv);
        int col = colbase + (__ffsll((long long)msk) - 1);
        if (lane == 63)
            sm.rmin[o * 2 + (wave & 1)] =
                ((u64)__float_as_uint(mv) << 32) | (unsigned)col;
    }
    __syncthreads();
    if (tid < OO) {
        u64 r0 = sm.rmin[tid * 2 + 0];
        u64 r1 = sm.rmin[tid * 2 + 1];
        rowmins[((size_t)b * NTILE + tile) * OO + tid] = r0 < r1 ? r0 : r1;
    }
    // No release protocol: kernel boundary on the stream is the fence.
}

// ---------------------------------------------------------------------------
// Kernel 2: JV LSA, 32 blocks (one per batch), VERBATIM the verified
// round-3/7/8 kernel (measured 138.5-139 us; r4 LDS-cache, r6 wave0-SAP and
// r2 auction all regressed -> this 4-wave structure is at its latency floor).
// ---------------------------------------------------------------------------
struct SML {
    URow   urow[TT];
    P2     path2[TT];                          // swizzled
    int    row4col[TT];
    int    claim[TT];
    int    col4row[OO];
    double u[OO];
    int    amin[OO];
    int    flag[OO];
    int    freelist[OO];
    int    selj[OO + 8];
    double selm[OO + 8];
    int    selrow[OO + 8];
    Cand   cand[2][4];
    int    nfree;
};

__global__ __launch_bounds__(NT) void hung_lsa_kernel(
    const float* __restrict__ cost,
    const u64* __restrict__ rowmins,
    int* __restrict__ out) {
#pragma clang fp contract(off)
    __shared__ SML sm;

    int b = blockIdx.x;
    int tid = threadIdx.x;
    int lane = tid & 63;
    int wave = tid >> 6;

    const float* cb = cost + (size_t)b * OO * TT;
    const int jbase = tid * SLOTS;

    double v_[SLOTS];
    double key[SLOTS];
    #pragma unroll
    for (int s = 0; s < SLOTS; ++s) v_[s] = 0.0;

    // ---- Phase A: u = row minima (combine the 16 tile results) ----
    if (tid < OO) {
        const u64* p = rowmins + (size_t)b * NTILE * OO + tid;
        u64 best = p[0];
        #pragma unroll
        for (int t = 1; t < NTILE; ++t) {
            u64 x = p[t * OO];
            if (x < best) best = x;
        }
        sm.u[tid] = (double)__uint_as_float((unsigned)(best >> 32));
        sm.amin[tid] = (int)(best & 0xFFFFFFFFull);
        sm.col4row[tid] = -1;
    }
    for (int j = tid; j < TT; j += NT) { sm.row4col[j] = -1; sm.claim[j] = 0x7FFFFFFF; }
    __syncthreads();

    // ---- Phase B: greedy tight pre-assignment (lowest row wins) ----
    if (tid < OO) atomicMin(&sm.claim[sm.amin[tid]], tid);
    __syncthreads();
    if (tid < OO) {
        int j = sm.amin[tid];
        if (sm.claim[j] == tid) { sm.col4row[tid] = j; sm.row4col[j] = tid; }
    }
    __syncthreads();

    // ---- Phase C: urow init + free-row list ----
    for (int j = tid; j < TT; j += NT) {
        int r = sm.row4col[j];
        URow t; t.row = r; t.u = (r >= 0) ? sm.u[r] : 0.0; t.pad = 0;
        sm.urow[j] = t;
    }
    if (tid < OO) sm.flag[tid] = (sm.col4row[tid] < 0) ? 1 : 0;
    __syncthreads();
    if (tid < OO && sm.flag[tid]) {
        int rank = 0;
        for (int o = 0; o < tid; ++o) rank += sm.flag[o];
        sm.freelist[rank] = tid;
    }
    if (tid == 0) {
        int nf = 0;
        for (int o = 0; o < OO; ++o) nf += sm.flag[o];
        sm.nfree = nf;
    }
    __syncthreads();
    int nfree = sm.nfree;

    // root-row prefetch for the first Dijkstra
    float4 pf0, pf1;
    if (nfree > 0) {
        const float* rr = cb + (size_t)sm.freelist[0] * TT + jbase;
        pf0 = *(const float4*)rr;
        pf1 = *(const float4*)(rr + 4);
    }

    // ---- Phase D: Dijkstra SAP ----
    int par = 0;
    for (int fi = 0; fi < nfree; ++fi) {
        int cur = sm.freelist[fi];

        #pragma unroll
        for (int s = 0; s < SLOTS; ++s) key[s] = INFINITY;
        int selbits = 0;
        double mv = 0.0;
        int i = cur, jc = -1;
        double ui = sm.u[cur];
        float4 c0 = pf0, c1 = pf1;
        int L = 0, sink;

        while (true) {
            float cv[SLOTS] = {c0.x, c0.y, c0.z, c0.w, c1.x, c1.y, c1.z, c1.w};
            double D = ui - mv;   // wave-uniform; one dependent op hoisted

            double bv = INFINITY;
            int bj = TT;
            #pragma unroll
            for (int s = 0; s < SLOTS; ++s) {
                if (!((selbits >> s) & 1)) {
                    double r = ((double)cv[s] - D) - v_[s];
                    if (r < key[s]) {
                        key[s] = r;
                        P2 p; p.i = i; p.j = jc;
                        sm.path2[s * NT + tid] = p;
                    }
                    double kk = key[s];
                    if (kk < bv) { bv = kk; bj = jbase + s; }
                }
            }
            dpp_lexmin<0x111>(bv, bj);
            dpp_lexmin<0x112>(bv, bj);
            dpp_lexmin<0x114>(bv, bj);
            dpp_lexmin<0x118>(bv, bj);
            dpp_lexmin<0x142>(bv, bj);
            dpp_lexmin<0x143>(bv, bj);
            int rlo = __builtin_amdgcn_readlane(__double2loint(bv), 63);
            int rhi = __builtin_amdgcn_readlane(__double2hiint(bv), 63);
            double wv = __hiloint2double(rhi, rlo);
            int wj = __builtin_amdgcn_readlane(bj, 63);

            // Pre-barrier urow fold-in: each wave reads its own candidate's
            // urow entry (read-only during the while loop); the LDS latency
            // overlaps other waves' barrier arrival.
            URow uwv = sm.urow[wj];            // wave-uniform b128 read

            par ^= 1;
            if (lane == 0) {
                Cand c; c.v = wv; c.u = uwv.u; c.j = wj; c.row = uwv.row;
                sm.cand[par][wave] = c;
            }
            __syncthreads();

            Cand cc0 = sm.cand[par][0];
            Cand cc1 = sm.cand[par][1];
            Cand cc2 = sm.cand[par][2];
            Cand cc3 = sm.cand[par][3];
            double MV = cc0.v; int BJ = cc0.j; int WR = cc0.row; double WU = cc0.u;
            if (cc1.v < MV || (cc1.v == MV && cc1.j < BJ)) { MV = cc1.v; BJ = cc1.j; WR = cc1.row; WU = cc1.u; }
            if (cc2.v < MV || (cc2.v == MV && cc2.j < BJ)) { MV = cc2.v; BJ = cc2.j; WR = cc2.row; WU = cc2.u; }
            if (cc3.v < MV || (cc3.v == MV && cc3.j < BJ)) { MV = cc3.v; BJ = cc3.j; WR = cc3.row; WU = cc3.u; }
            mv = MV;
            if ((BJ >> 3) == tid) selbits |= 1 << (BJ & 7);
            if (tid == 0) sm.selj[L] = BJ;

            if (WR < 0) { sink = BJ; break; }
            if (tid == 0) { sm.selm[L] = MV; sm.selrow[L] = WR; }
            i = WR; ui = WU; jc = BJ;
            L++;
            const float* crow = cb + (size_t)i * TT + jbase;
            c0 = *(const float4*)crow;
            c1 = *(const float4*)(crow + 4);
        }

        // prefetch next Dijkstra's root row (off the critical path)
        if (fi + 1 < nfree) {
            const float* rr = cb + (size_t)sm.freelist[fi + 1] * TT + jbase;
            pf0 = *(const float4*)rr;
            pf1 = *(const float4*)(rr + 4);
        }

        double M = mv;
        #pragma unroll
        for (int s = 0; s < SLOTS; ++s)
            if ((selbits >> s) & 1) v_[s] = v_[s] - (M - key[s]);
        for (int k = tid; k < L; k += NT)
            sm.u[sm.selrow[k]] = sm.u[sm.selrow[k]] + (M - sm.selm[k]);
        if (tid == 0) {
            sm.u[cur] = sm.u[cur] + M;
            int j = sink;
            while (true) {
                P2 p = sm.path2[(j & 7) * NT + (j >> 3)];
                int ii = p.i;
                sm.row4col[j] = ii;
                sm.col4row[ii] = j;
                if (ii == cur) break;
                j = p.j;
            }
        }
        __syncthreads();
        if (tid <= L) {
            int j = sm.selj[tid];
            int r = sm.row4col[j];
            URow t; t.u = sm.u[r]; t.row = r; t.pad = 0;
            sm.urow[j] = t;
        }
        __syncthreads();
    }

    // order = argsort(col4row); pred_idx = col4row[order]; tgt_idx = order
    if (tid < OO) {
        int my = sm.col4row[tid];
        int rank = 0;
        for (int o = 0; o < OO; ++o) rank += (sm.col4row[o] < my) ? 1 : 0;
        out[(size_t)b * OO + rank] = my;         // pred_idx
        out[(size_t)(BB + b) * OO + rank] = tid; // tgt_idx
    }
}

// ---------------------------------------------------------------------------
extern "C" void kernel_launch(void* const* d_in, const int* in_sizes, int n_in,
                              void* d_out, int out_size, void* d_ws, size_t ws_size,
                              hipStream_t stream) {
    const float* pred_bboxes = (const float*)d_in[0];    // [B,T,4]
    const float* target_bboxes = (const float*)d_in[1];  // [B,O,4]
    const float* pred_classes = (const float*)d_in[2];   // [B,T,C]
    const int* target_classes = (const int*)d_in[3];     // [B,O]
    int* out = (int*)d_out;                              // [2,B,O] int32

    float* cost = (float*)d_ws;  // [B][O][T] fp32 (32 MB)
    u64* rowmins = (u64*)(cost + (size_t)BB * OO * TT);  // [B][NTILE][O]

    hung_cost_kernel<<<BB * NTILE, NTP, 0, stream>>>(
        pred_bboxes, target_bboxes, pred_classes, target_classes, cost, rowmins);
    hung_lsa_kernel<<<BB, NT, 0, stream>>>(cost, rowmins, out);
}